// Round 8
// baseline (57131.726 us; speedup 1.0000x reference)
//
#include <hip/hip_runtime.h>
#include <hip/hip_bf16.h>
#include <stdint.h>

// Problem dims
#define B_  64
#define T_  1024
#define F_  512
#define U_  1024
#define G4_ 4096
#define C_  1000
#define CT_ 16          // timesteps per xz chunk
#define NCH_ (T_ / CT_) // 64 chunks

typedef __bf16 bf16x8 __attribute__((ext_vector_type(8)));
typedef float  f32x4  __attribute__((ext_vector_type(4)));
typedef unsigned short u16x8 __attribute__((ext_vector_type(8)));

static __device__ __forceinline__ unsigned short f2bf(float f) {
  __hip_bfloat16 h = __float2bfloat16(f);
  return __builtin_bit_cast(unsigned short, h);
}
static __device__ __forceinline__ float bf2f(unsigned short u) {
  return __uint_as_float(((unsigned)u) << 16);
}
static __device__ __forceinline__ float sig1(float x) {
  return 1.f / (1.f + __expf(-x));
}
static __device__ __forceinline__ float tanh1(float x) {
  float ax = fabsf(x);
  float e  = __expf(2.f * ax);
  float r  = (e - 1.f) / (e + 1.f);
  r = (ax > 15.f) ? 1.f : r;
  return copysignf(r, x);
}

static __device__ __forceinline__ void gload_lds16(const void* g, void* l) {
  __builtin_amdgcn_global_load_lds(
      (const __attribute__((address_space(1))) unsigned int*)g,
      (__attribute__((address_space(3))) unsigned int*)l, 16, 0, 0);
}

// ---------------- K1a/b: f32 [R][C] -> bf16 [C][R] transpose ----------------
__global__ __launch_bounds__(256) void k_transpose_bf16(
    const float* __restrict__ in, unsigned short* __restrict__ out, int R, int C) {
  __shared__ float tile[64][65];
  int c0 = blockIdx.x * 64, r0 = blockIdx.y * 64;
  int tid = threadIdx.x;
  int tr = tid >> 4, tc4 = (tid & 15) * 4;
#pragma unroll
  for (int rr = 0; rr < 64; rr += 16) {
    float4 v = *(const float4*)&in[(size_t)(r0 + rr + tr) * C + c0 + tc4];
    tile[rr + tr][tc4 + 0] = v.x;
    tile[rr + tr][tc4 + 1] = v.y;
    tile[rr + tr][tc4 + 2] = v.z;
    tile[rr + tr][tc4 + 3] = v.w;
  }
  __syncthreads();
#pragma unroll
  for (int cc = 0; cc < 64; cc += 16) {
    int c = cc + tr;
    int r = tc4;
    ushort4 o;
    o.x = f2bf(tile[r + 0][c]);
    o.y = f2bf(tile[r + 1][c]);
    o.z = f2bf(tile[r + 2][c]);
    o.w = f2bf(tile[r + 3][c]);
    *(ushort4*)&out[(size_t)(c0 + c) * R + r0 + r] = o;
  }
}

// ================= PERSISTENT KERNEL =================
// grid 256 = 4 groups (g = bx>>6, 16 samples each) x 64 blocks (b6 = bx&63).
// Per chunk: GEMM phase (b6 -> tile mt=b6>>5, bn=b6&31; M=256 rows = t'(16)x bl(16))
// then 16 step phases (b6 = wblk). Group-local barrier after each phase.
// Regular (non-cooperative) launch: grid == #CUs, 1 block/CU -> co-resident on
// an idle exclusive GPU. Watchdog converts any residency failure into a wrong
// answer (sticky `dead` flag) instead of a device hang.
__global__ __launch_bounds__(256) void k_persist(
    const float* __restrict__ x,              // [64][1024][512] f32
    const unsigned short* __restrict__ wkt,   // [4096][512] bf16
    const unsigned short* __restrict__ wrt,   // [4096][1024] bf16
    const float* __restrict__ bias,           // [4096] f32
    unsigned short* __restrict__ xzg,         // [4][16][256][64][4] bf16 (per-chunk slot)
    unsigned short* __restrict__ hb,          // 2 x [64][1024] bf16
    float* __restrict__ hf,                   // [64][1024] f32
    unsigned int* __restrict__ syncb) {
  __shared__ char smem[65536];
  unsigned short (*As)[8192] = reinterpret_cast<unsigned short(*)[8192]>(smem);
  unsigned short (*Bs)[8192] = reinterpret_cast<unsigned short(*)[8192]>(smem + 32768);
  f32x4 (*pbuf)[4][64] = reinterpret_cast<f32x4(*)[4][64]>(smem);          // 16KB (step phase)
  f32x4 (*gbuf)[64]    = reinterpret_cast<f32x4(*)[64]>(smem + 16384);     // 4KB  (step phase)

  const int bx = blockIdx.x;
  const int g = bx >> 6, b6 = bx & 63;
  const int tid = threadIdx.x;
  const int w = tid >> 6, l = tid & 63;
  unsigned int* cnt = syncb + g * 16;   // 64B-separated per-group counters
  unsigned epoch = 0;
  int dead = 0;                          // watchdog sticky flag (tid0 only)

  auto gbar = [&]() {
    __threadfence();
    __syncthreads();
    ++epoch;
    if (tid == 0 && !dead) {
      __hip_atomic_fetch_add(cnt, 1u, __ATOMIC_RELEASE, __HIP_MEMORY_SCOPE_AGENT);
      unsigned tgt = epoch * 64u;
      int spins = 0;
      while (__hip_atomic_load(cnt, __ATOMIC_ACQUIRE, __HIP_MEMORY_SCOPE_AGENT) < tgt) {
        __builtin_amdgcn_s_sleep(8);
        if (++spins > 4000000) { dead = 1; break; }   // ~0.8s -> degrade, don't hang
      }
    }
    __syncthreads();
    __threadfence();
  };

  // zero h slot 0 (this block's 16x16 slice) ; c state in register
  {
    int m = tid >> 4, u = tid & 15;
    hb[((size_t)(g * 16 + m) << 10) + b6 * 16 + u] = 0;
  }
  float creg = 0.f;

  // GEMM role constants
  const int mt = b6 >> 5, bn = b6 & 31;
  const int wr = w >> 1, wc = w & 1;
  const int r8 = l >> 3, ch = l & 7;
  // step role constants
  const int w4 = w, l15 = l & 15, lk = (l >> 4) * 8;
  const int kb = w4 * 256;

  for (int c = 0; c < NCH_; ++c) {
    const int t0 = c * CT_;
    // ================= GEMM phase: xz chunk for this group =================
    f32x4 acc[4][4];
#pragma unroll
    for (int i = 0; i < 4; ++i)
#pragma unroll
      for (int j = 0; j < 4; ++j) acc[i][j] = f32x4{0.f, 0.f, 0.f, 0.f};

    float4 av[4][2];
    auto loadA = [&](int kt) {
#pragma unroll
      for (int p = 0; p < 4; ++p) {
        int r = w * 32 + p * 8 + r8;        // tile-local row
        int R = mt * 128 + r;               // group row: t' = R>>4, bl = R&15
        size_t base = ((size_t)(g * 16 + (R & 15)) * T_ + t0 + (R >> 4)) * F_ + kt * 64 + ch * 8;
        av[p][0] = *(const float4*)&x[base];
        av[p][1] = *(const float4*)&x[base + 4];
      }
    };
    auto writeA = [&](int buf) {
#pragma unroll
      for (int p = 0; p < 4; ++p) {
        int r = w * 32 + p * 8 + r8;
        int chs = ch ^ (r & 7);
        u16x8 o;
        o[0] = f2bf(av[p][0].x); o[1] = f2bf(av[p][0].y);
        o[2] = f2bf(av[p][0].z); o[3] = f2bf(av[p][0].w);
        o[4] = f2bf(av[p][1].x); o[5] = f2bf(av[p][1].y);
        o[6] = f2bf(av[p][1].z); o[7] = f2bf(av[p][1].w);
        *(u16x8*)((char*)As[buf] + r * 128 + chs * 16) = o;
      }
    };
    auto stageB = [&](int buf, int kt) {
#pragma unroll
      for (int i = 0; i < 4; ++i) {
        int row = w * 32 + i * 8 + r8;
        int chs = ch ^ (row & 7);
        gload_lds16((const char*)wkt + (size_t)(bn * 128 + row) * 1024 + kt * 128 + chs * 16,
                    (char*)Bs[buf] + (size_t)(w * 32 + i * 8) * 128);
      }
    };

    loadA(0);
    writeA(0);
    stageB(0, 0);
    __syncthreads();
    for (int kt = 0; kt < 8; ++kt) {
      int cur = kt & 1;
      if (kt < 7) {
        loadA(kt + 1);
        stageB(cur ^ 1, kt + 1);
      }
      bf16x8 af[4][2], bfr[4][2];
#pragma unroll
      for (int ks = 0; ks < 2; ++ks) {
#pragma unroll
        for (int mi = 0; mi < 4; ++mi) {
          int rowa = wr * 64 + mi * 16 + (l & 15);
          int cha = (ks * 4 + (l >> 4)) ^ (rowa & 7);
          af[mi][ks] = *(const bf16x8*)((const char*)As[cur] + rowa * 128 + cha * 16);
          int rowb = wc * 64 + mi * 16 + (l & 15);
          int chb = (ks * 4 + (l >> 4)) ^ (rowb & 7);
          bfr[mi][ks] = *(const bf16x8*)((const char*)Bs[cur] + rowb * 128 + chb * 16);
        }
      }
#pragma unroll
      for (int mi = 0; mi < 4; ++mi)
#pragma unroll
        for (int ni = 0; ni < 4; ++ni)
#pragma unroll
          for (int ks = 0; ks < 2; ++ks)
            acc[mi][ni] = __builtin_amdgcn_mfma_f32_16x16x32_bf16(
                af[mi][ks], bfr[ni][ks], acc[mi][ni], 0, 0, 0);
      if (kt < 7) writeA(cur ^ 1);
      __syncthreads();
    }
    // epilogue: frag dump. tile t' = mt*8 + wr*4 + mi ; nt = bn*8 + wc*4 + ni
#pragma unroll
    for (int mi = 0; mi < 4; ++mi) {
      int tp = mt * 8 + wr * 4 + mi;
#pragma unroll
      for (int ni = 0; ni < 4; ++ni) {
        int nt = bn * 8 + wc * 4 + ni;
        ushort4 o;
        o.x = f2bf(acc[mi][ni][0]);
        o.y = f2bf(acc[mi][ni][1]);
        o.z = f2bf(acc[mi][ni][2]);
        o.w = f2bf(acc[mi][ni][3]);
        *(ushort4*)&xzg[((((size_t)g * 16 + tp) * 256 + nt) * 64 + l) * 4] = o;
      }
    }
    gbar();   // xz chunk visible to group

    // ================= 16 LSTM steps =================
    for (int tt = 0; tt < CT_; ++tt) {
      int t = t0 + tt;
      const unsigned short* hc = hb + (size_t)(t & 1) * 65536;
      unsigned short* hn = hb + (size_t)((t + 1) & 1) * 65536;

      ushort4 xv = *(const ushort4*)&xzg[((((size_t)g * 16 + tt) * 256 + (w4 * 64 + b6)) * 64 + l) * 4];
      float bv = bias[w4 * 1024 + b6 * 16 + l15];
      const unsigned short* ap = hc + (size_t)(g * 16 + l15) * 1024 + kb + lk;
      const unsigned short* bp = wrt + (size_t)(b6 * 16 + l15) * 1024 + kb + lk;

      f32x4 a0 = f32x4{0.f, 0.f, 0.f, 0.f}, a1 = a0, a2 = a0, a3 = a0;
#pragma unroll
      for (int ks = 0; ks < 8; ++ks) {
        bf16x8 a  = *(const bf16x8*)(ap + ks * 32);
        bf16x8 b0 = *(const bf16x8*)(bp + 0 * 1048576 + ks * 32);
        bf16x8 b1 = *(const bf16x8*)(bp + 1 * 1048576 + ks * 32);
        bf16x8 b2 = *(const bf16x8*)(bp + 2 * 1048576 + ks * 32);
        bf16x8 b3 = *(const bf16x8*)(bp + 3 * 1048576 + ks * 32);
        a0 = __builtin_amdgcn_mfma_f32_16x16x32_bf16(a, b0, a0, 0, 0, 0);
        a1 = __builtin_amdgcn_mfma_f32_16x16x32_bf16(a, b1, a1, 0, 0, 0);
        a2 = __builtin_amdgcn_mfma_f32_16x16x32_bf16(a, b2, a2, 0, 0, 0);
        a3 = __builtin_amdgcn_mfma_f32_16x16x32_bf16(a, b3, a3, 0, 0, 0);
      }
      pbuf[w4][0][l] = a0;
      pbuf[w4][1][l] = a1;
      pbuf[w4][2][l] = a2;
      pbuf[w4][3][l] = a3;
      __syncthreads();

      f32x4 z = pbuf[0][w4][l];
      z += pbuf[1][w4][l];
      z += pbuf[2][w4][l];
      z += pbuf[3][w4][l];
      z[0] += bf2f(xv.x) + bv;
      z[1] += bf2f(xv.y) + bv;
      z[2] += bf2f(xv.z) + bv;
      z[3] += bf2f(xv.w) + bv;
      if (w4 == 2) {
#pragma unroll
        for (int j = 0; j < 4; ++j) z[j] = tanh1(z[j]);
      } else {
#pragma unroll
        for (int j = 0; j < 4; ++j) z[j] = sig1(z[j]);
      }
      gbuf[w4][l] = z;
      __syncthreads();

      int m = tid >> 4, u = tid & 15;
      int l2 = ((m >> 2) << 4) | u, j2 = m & 3;
      float iv = gbuf[0][l2][j2];
      float fv = gbuf[1][l2][j2];
      float gv = gbuf[2][l2][j2];
      float ov = gbuf[3][l2][j2];
      creg = fv * creg + iv * gv;
      float h = ov * tanh1(creg);
      size_t hidx = (size_t)(g * 16 + m) * 1024 + b6 * 16 + u;
      hn[hidx] = f2bf(h);
      if (t == T_ - 1) hf[hidx] = h;
      gbar();   // h(t+1) visible to group
    }
  }
}

// ---------------- K4: logits = h@Wd + bd, softmax ----------------
__global__ __launch_bounds__(256) void k_final(
    const float* __restrict__ hfin, const float* __restrict__ Wd,
    const float* __restrict__ bd, float* __restrict__ out) {
  __shared__ float hrow[1024];
  __shared__ float red[256];
  int b = blockIdx.x, tid = threadIdx.x;
  float4 hv = *(const float4*)&hfin[(size_t)b * 1024 + tid * 4];
  hrow[tid * 4 + 0] = hv.x;
  hrow[tid * 4 + 1] = hv.y;
  hrow[tid * 4 + 2] = hv.z;
  hrow[tid * 4 + 3] = hv.w;
  __syncthreads();
  float vals[4];
#pragma unroll
  for (int chn = 0; chn < 4; ++chn) {
    int c = chn * 256 + tid;
    float a = -1e30f;
    if (c < C_) {
      a = bd[c];
#pragma unroll 4
      for (int k = 0; k < 1024; ++k) a += hrow[k] * Wd[k * 1000 + c];
    }
    vals[chn] = a;
  }
  float mx = fmaxf(fmaxf(vals[0], vals[1]), fmaxf(vals[2], vals[3]));
  red[tid] = mx;
  __syncthreads();
  for (int s = 128; s > 0; s >>= 1) {
    if (tid < s) red[tid] = fmaxf(red[tid], red[tid + s]);
    __syncthreads();
  }
  float M = red[0];
  __syncthreads();
  float ex[4];
  float sm = 0.f;
#pragma unroll
  for (int chn = 0; chn < 4; ++chn) {
    int c = chn * 256 + tid;
    ex[chn] = (c < C_) ? __expf(vals[chn] - M) : 0.f;
    sm += ex[chn];
  }
  red[tid] = sm;
  __syncthreads();
  for (int s = 128; s > 0; s >>= 1) {
    if (tid < s) red[tid] += red[tid + s];
    __syncthreads();
  }
  float inv = 1.f / red[0];
#pragma unroll
  for (int chn = 0; chn < 4; ++chn) {
    int c = chn * 256 + tid;
    if (c < C_) out[(size_t)b * C_ + c] = ex[chn] * inv;
  }
}

// ---------------- launch ----------------
extern "C" void kernel_launch(void* const* d_in, const int* in_sizes, int n_in,
                              void* d_out, int out_size, void* d_ws, size_t ws_size,
                              hipStream_t stream) {
  const float* x    = (const float*)d_in[0];
  const float* Wk   = (const float*)d_in[1];
  const float* Wr   = (const float*)d_in[2];
  const float* bias = (const float*)d_in[3];
  const float* Wd   = (const float*)d_in[4];
  const float* bd   = (const float*)d_in[5];
  float* out = (float*)d_out;

  // ws layout (bytes)
  const size_t OFF_WKT  = 0;          // 4,194,304
  const size_t OFF_WRT  = 4194304;    // 8,388,608
  const size_t OFF_XZG  = 12582912;   // 8,388,608
  const size_t OFF_HB   = 31457280;   // 262,144
  const size_t OFF_SY   = 31719424;   // 262,144 (sync counters)
  const size_t OFF_HF   = 31981568;   // 262,144
  const size_t NEED     = 32243712;

  if (ws_size < NEED) {
    hipMemsetAsync(d_out, 0x7F, (size_t)out_size * sizeof(float), stream);
    return;
  }

  char* ws = (char*)d_ws;
  unsigned short* WKT = (unsigned short*)(ws + OFF_WKT);
  unsigned short* WRT = (unsigned short*)(ws + OFF_WRT);
  unsigned short* XZG = (unsigned short*)(ws + OFF_XZG);
  unsigned short* HB  = (unsigned short*)(ws + OFF_HB);
  unsigned int* SYNC  = (unsigned int*)(ws + OFF_SY);
  float* HF = (float*)(ws + OFF_HF);

  hipMemsetAsync(HB, 0, 131072, stream);    // h0 = 0 (slot 0)
  hipMemsetAsync(SYNC, 0, 262144, stream);  // barrier counters

  k_transpose_bf16<<<dim3(G4_ / 64, F_ / 64), 256, 0, stream>>>(Wk, WKT, F_, G4_);
  k_transpose_bf16<<<dim3(G4_ / 64, U_ / 64), 256, 0, stream>>>(Wr, WRT, U_, G4_);

  // persistent fused recurrence: regular launch (graph-capturable), grid == #CUs
  k_persist<<<256, 256, 0, stream>>>(x, WKT, WRT, bias, XZG, HB, HF, SYNC);

  k_final<<<64, 256, 0, stream>>>(HF, Wd, bd, out);
}

// Round 9
// 7426.434 us; speedup vs baseline: 7.6930x; 7.6930x over previous
//
#include <hip/hip_runtime.h>
#include <hip/hip_bf16.h>
#include <stdint.h>

// Problem dims
#define B_  64
#define T_  1024
#define F_  512
#define U_  1024
#define G4_ 4096
#define C_  1000
#define CT_ 16          // timesteps per xz chunk
#define NCH_ (T_ / CT_) // 64 chunks

typedef __bf16 bf16x8 __attribute__((ext_vector_type(8)));
typedef float  f32x4  __attribute__((ext_vector_type(4)));
typedef unsigned short u16x8 __attribute__((ext_vector_type(8)));
typedef unsigned long long u64;

static __device__ __forceinline__ unsigned short f2bf(float f) {
  __hip_bfloat16 h = __float2bfloat16(f);
  return __builtin_bit_cast(unsigned short, h);
}
static __device__ __forceinline__ float bf2f(unsigned short u) {
  return __uint_as_float(((unsigned)u) << 16);
}
static __device__ __forceinline__ float sig1(float x) {
  return 1.f / (1.f + __expf(-x));
}
static __device__ __forceinline__ float tanh1(float x) {
  float ax = fabsf(x);
  float e  = __expf(2.f * ax);
  float r  = (e - 1.f) / (e + 1.f);
  r = (ax > 15.f) ? 1.f : r;
  return copysignf(r, x);
}

static __device__ __forceinline__ void gload_lds16(const void* g, void* l) {
  __builtin_amdgcn_global_load_lds(
      (const __attribute__((address_space(1))) unsigned int*)g,
      (__attribute__((address_space(3))) unsigned int*)l, 16, 0, 0);
}

// Relaxed agent-scope atomics: compile to sc0/sc1 bypass accesses coherent at
// L3 — NO buffer_inv / buffer_wbl2 (those come only from acquire/release).
static __device__ __forceinline__ void at_store64(void* p, u64 v) {
  __hip_atomic_store((u64*)p, v, __ATOMIC_RELAXED, __HIP_MEMORY_SCOPE_AGENT);
}
static __device__ __forceinline__ u64 at_load64(const void* p) {
  return __hip_atomic_load((const u64*)p, __ATOMIC_RELAXED, __HIP_MEMORY_SCOPE_AGENT);
}
static __device__ __forceinline__ void at_store32(void* p, unsigned v) {
  __hip_atomic_store((unsigned*)p, v, __ATOMIC_RELAXED, __HIP_MEMORY_SCOPE_AGENT);
}
static __device__ __forceinline__ unsigned at_load32(const void* p) {
  return __hip_atomic_load((const unsigned*)p, __ATOMIC_RELAXED, __HIP_MEMORY_SCOPE_AGENT);
}

// ---------------- K1a/b: f32 [R][C] -> bf16 [C][R] transpose ----------------
__global__ __launch_bounds__(256) void k_transpose_bf16(
    const float* __restrict__ in, unsigned short* __restrict__ out, int R, int C) {
  __shared__ float tile[64][65];
  int c0 = blockIdx.x * 64, r0 = blockIdx.y * 64;
  int tid = threadIdx.x;
  int tr = tid >> 4, tc4 = (tid & 15) * 4;
#pragma unroll
  for (int rr = 0; rr < 64; rr += 16) {
    float4 v = *(const float4*)&in[(size_t)(r0 + rr + tr) * C + c0 + tc4];
    tile[rr + tr][tc4 + 0] = v.x;
    tile[rr + tr][tc4 + 1] = v.y;
    tile[rr + tr][tc4 + 2] = v.z;
    tile[rr + tr][tc4 + 3] = v.w;
  }
  __syncthreads();
#pragma unroll
  for (int cc = 0; cc < 64; cc += 16) {
    int c = cc + tr;
    int r = tc4;
    ushort4 o;
    o.x = f2bf(tile[r + 0][c]);
    o.y = f2bf(tile[r + 1][c]);
    o.z = f2bf(tile[r + 2][c]);
    o.w = f2bf(tile[r + 3][c]);
    *(ushort4*)&out[(size_t)(c0 + c) * R + r0 + r] = o;
  }
}

// ================= PERSISTENT KERNEL (fence-free sync) =================
// grid 256 = 4 groups (g = bx>>6, 16 samples each) x 64 blocks (b6 = bx&63).
// Cross-block data (xz, h) via relaxed agent atomics (L3-coherent bypass);
// weights via normal cached loads -> L2 never invalidated, Wr stays resident.
__global__ __launch_bounds__(256) void k_persist(
    const float* __restrict__ x,              // [64][1024][512] f32
    const unsigned short* __restrict__ wkt,   // [4096][512] bf16
    const unsigned short* __restrict__ wrt,   // [4096][1024] bf16
    const float* __restrict__ bias,           // [4096] f32
    unsigned short* __restrict__ xzg,         // [4][16][256][64][4] bf16 (per-chunk slot)
    unsigned short* __restrict__ hb,          // 2 x [64][1024] bf16
    float* __restrict__ hf,                   // [64][1024] f32
    unsigned int* __restrict__ syncb) {
  __shared__ char smem[65536];
  unsigned short (*As)[8192] = reinterpret_cast<unsigned short(*)[8192]>(smem);
  unsigned short (*Bs)[8192] = reinterpret_cast<unsigned short(*)[8192]>(smem + 32768);
  f32x4 (*pbuf)[4][64] = reinterpret_cast<f32x4(*)[4][64]>(smem);          // 16KB (step phase)
  f32x4 (*gbuf)[64]    = reinterpret_cast<f32x4(*)[64]>(smem + 16384);     // 4KB  (step phase)
  unsigned short* hst  = reinterpret_cast<unsigned short*>(smem + 20480);  // 512B (step phase)

  const int bx = blockIdx.x;
  const int g = bx >> 6, b6 = bx & 63;
  const int tid = threadIdx.x;
  const int w = tid >> 6, l = tid & 63;
  unsigned int* cnt = syncb + g * 16;   // 64B-separated per-group counters
  unsigned epoch = 0;
  int dead = 0;                          // watchdog sticky flag (tid0 only)

  auto gbar = [&]() {
    asm volatile("s_waitcnt vmcnt(0)" ::: "memory");  // drain bypass-stores to L3
    __syncthreads();
    ++epoch;
    if (tid == 0) {
      __hip_atomic_fetch_add(cnt, 1u, __ATOMIC_RELAXED, __HIP_MEMORY_SCOPE_AGENT);
      if (!dead) {
        unsigned tgt = epoch * 64u;
        int spins = 0;
        while (at_load32(cnt) < tgt) {
          __builtin_amdgcn_s_sleep(2);
          if (++spins > 2000000) { dead = 1; break; }  // ~0.5s -> degrade, don't hang
        }
      }
    }
    __syncthreads();
  };

  // zero h slot 0 (this block's 16x16 slice) via bypass stores; c in register
  if (tid < 128) {
    int idx = tid << 1;
    int m2 = idx >> 4, u2 = idx & 15;
    at_store32(&hb[(size_t)(g * 16 + m2) * 1024 + b6 * 16 + u2], 0u);
  }
  float creg = 0.f;

  // GEMM role constants
  const int mt = b6 >> 5, bn = b6 & 31;
  const int wr = w >> 1, wc = w & 1;
  const int r8 = l >> 3, ch = l & 7;
  // step role constants
  const int w4 = w, l15 = l & 15, lk = (l >> 4) * 8;
  const int kb = w4 * 256;

  for (int c = 0; c < NCH_; ++c) {
    const int t0 = c * CT_;
    // ================= GEMM phase: xz chunk for this group =================
    f32x4 acc[4][4];
#pragma unroll
    for (int i = 0; i < 4; ++i)
#pragma unroll
      for (int j = 0; j < 4; ++j) acc[i][j] = f32x4{0.f, 0.f, 0.f, 0.f};

    float4 av[4][2];
    auto loadA = [&](int kt) {
#pragma unroll
      for (int p = 0; p < 4; ++p) {
        int r = w * 32 + p * 8 + r8;        // tile-local row
        int R = mt * 128 + r;               // group row: t' = R>>4, bl = R&15
        size_t base = ((size_t)(g * 16 + (R & 15)) * T_ + t0 + (R >> 4)) * F_ + kt * 64 + ch * 8;
        av[p][0] = *(const float4*)&x[base];
        av[p][1] = *(const float4*)&x[base + 4];
      }
    };
    auto writeA = [&](int buf) {
#pragma unroll
      for (int p = 0; p < 4; ++p) {
        int r = w * 32 + p * 8 + r8;
        int chs = ch ^ (r & 7);
        u16x8 o;
        o[0] = f2bf(av[p][0].x); o[1] = f2bf(av[p][0].y);
        o[2] = f2bf(av[p][0].z); o[3] = f2bf(av[p][0].w);
        o[4] = f2bf(av[p][1].x); o[5] = f2bf(av[p][1].y);
        o[6] = f2bf(av[p][1].z); o[7] = f2bf(av[p][1].w);
        *(u16x8*)((char*)As[buf] + r * 128 + chs * 16) = o;
      }
    };
    auto stageB = [&](int buf, int kt) {
#pragma unroll
      for (int i = 0; i < 4; ++i) {
        int row = w * 32 + i * 8 + r8;
        int chs = ch ^ (row & 7);
        gload_lds16((const char*)wkt + (size_t)(bn * 128 + row) * 1024 + kt * 128 + chs * 16,
                    (char*)Bs[buf] + (size_t)(w * 32 + i * 8) * 128);
      }
    };

    loadA(0);
    writeA(0);
    stageB(0, 0);
    __syncthreads();
    for (int kt = 0; kt < 8; ++kt) {
      int cur = kt & 1;
      if (kt < 7) {
        loadA(kt + 1);
        stageB(cur ^ 1, kt + 1);
      }
      bf16x8 af[4][2], bfr[4][2];
#pragma unroll
      for (int ks = 0; ks < 2; ++ks) {
#pragma unroll
        for (int mi = 0; mi < 4; ++mi) {
          int rowa = wr * 64 + mi * 16 + (l & 15);
          int cha = (ks * 4 + (l >> 4)) ^ (rowa & 7);
          af[mi][ks] = *(const bf16x8*)((const char*)As[cur] + rowa * 128 + cha * 16);
          int rowb = wc * 64 + mi * 16 + (l & 15);
          int chb = (ks * 4 + (l >> 4)) ^ (rowb & 7);
          bfr[mi][ks] = *(const bf16x8*)((const char*)Bs[cur] + rowb * 128 + chb * 16);
        }
      }
#pragma unroll
      for (int mi = 0; mi < 4; ++mi)
#pragma unroll
        for (int ni = 0; ni < 4; ++ni)
#pragma unroll
          for (int ks = 0; ks < 2; ++ks)
            acc[mi][ni] = __builtin_amdgcn_mfma_f32_16x16x32_bf16(
                af[mi][ks], bfr[ni][ks], acc[mi][ni], 0, 0, 0);
      if (kt < 7) writeA(cur ^ 1);
      __syncthreads();
    }
    // epilogue: frag dump (bypass u64 stores). t' = mt*8+wr*4+mi ; nt = bn*8+wc*4+ni
#pragma unroll
    for (int mi = 0; mi < 4; ++mi) {
      int tp = mt * 8 + wr * 4 + mi;
#pragma unroll
      for (int ni = 0; ni < 4; ++ni) {
        int nt = bn * 8 + wc * 4 + ni;
        u64 pack = (u64)f2bf(acc[mi][ni][0]) | ((u64)f2bf(acc[mi][ni][1]) << 16) |
                   ((u64)f2bf(acc[mi][ni][2]) << 32) | ((u64)f2bf(acc[mi][ni][3]) << 48);
        at_store64(&xzg[((((size_t)g * 16 + tp) * 256 + nt) * 64 + l) * 4], pack);
      }
    }
    gbar();   // xz chunk visible to group

    // ================= 16 LSTM steps =================
    for (int tt = 0; tt < CT_; ++tt) {
      int t = t0 + tt;
      const unsigned short* hc = hb + (size_t)(t & 1) * 65536;
      unsigned short* hn = hb + (size_t)((t + 1) & 1) * 65536;

      u64 xq = at_load64(&xzg[((((size_t)g * 16 + tt) * 256 + (w4 * 64 + b6)) * 64 + l) * 4]);
      float bv = bias[w4 * 1024 + b6 * 16 + l15];
      const unsigned short* ap = hc + (size_t)(g * 16 + l15) * 1024 + kb + lk;
      const unsigned short* bp = wrt + (size_t)(b6 * 16 + l15) * 1024 + kb + lk;

      f32x4 a0 = f32x4{0.f, 0.f, 0.f, 0.f}, a1 = a0, a2 = a0, a3 = a0;
#pragma unroll
      for (int ks = 0; ks < 8; ++ks) {
        union { u64 q[2]; bf16x8 v; } ua;
        ua.q[0] = at_load64(ap + ks * 32);
        ua.q[1] = at_load64(ap + ks * 32 + 4);
        bf16x8 a  = ua.v;
        bf16x8 b0 = *(const bf16x8*)(bp + 0 * 1048576 + ks * 32);
        bf16x8 b1 = *(const bf16x8*)(bp + 1 * 1048576 + ks * 32);
        bf16x8 b2 = *(const bf16x8*)(bp + 2 * 1048576 + ks * 32);
        bf16x8 b3 = *(const bf16x8*)(bp + 3 * 1048576 + ks * 32);
        a0 = __builtin_amdgcn_mfma_f32_16x16x32_bf16(a, b0, a0, 0, 0, 0);
        a1 = __builtin_amdgcn_mfma_f32_16x16x32_bf16(a, b1, a1, 0, 0, 0);
        a2 = __builtin_amdgcn_mfma_f32_16x16x32_bf16(a, b2, a2, 0, 0, 0);
        a3 = __builtin_amdgcn_mfma_f32_16x16x32_bf16(a, b3, a3, 0, 0, 0);
      }
      pbuf[w4][0][l] = a0;
      pbuf[w4][1][l] = a1;
      pbuf[w4][2][l] = a2;
      pbuf[w4][3][l] = a3;
      __syncthreads();

      f32x4 z = pbuf[0][w4][l];
      z += pbuf[1][w4][l];
      z += pbuf[2][w4][l];
      z += pbuf[3][w4][l];
      z[0] += bf2f((unsigned short)(xq)) + bv;
      z[1] += bf2f((unsigned short)(xq >> 16)) + bv;
      z[2] += bf2f((unsigned short)(xq >> 32)) + bv;
      z[3] += bf2f((unsigned short)(xq >> 48)) + bv;
      if (w4 == 2) {
#pragma unroll
        for (int j = 0; j < 4; ++j) z[j] = tanh1(z[j]);
      } else {
#pragma unroll
        for (int j = 0; j < 4; ++j) z[j] = sig1(z[j]);
      }
      gbuf[w4][l] = z;
      __syncthreads();

      int m = tid >> 4, u = tid & 15;
      int l2 = ((m >> 2) << 4) | u, j2 = m & 3;
      float iv = gbuf[0][l2][j2];
      float fv = gbuf[1][l2][j2];
      float gv = gbuf[2][l2][j2];
      float ov = gbuf[3][l2][j2];
      creg = fv * creg + iv * gv;
      float h = ov * tanh1(creg);
      hst[tid] = f2bf(h);                               // tid == m*16+u
      if (t == T_ - 1) hf[(size_t)(g * 16 + m) * 1024 + b6 * 16 + u] = h;
      __syncthreads();
      if (tid < 128) {                                  // paired bypass u32 stores
        int idx = tid << 1;
        unsigned v = (unsigned)hst[idx] | ((unsigned)hst[idx + 1] << 16);
        int m2 = idx >> 4, u2 = idx & 15;
        at_store32(&hn[(size_t)(g * 16 + m2) * 1024 + b6 * 16 + u2], v);
      }
      gbar();   // h(t+1) visible to group
    }
  }
}

// ---------------- K4: logits = h@Wd + bd, softmax ----------------
__global__ __launch_bounds__(256) void k_final(
    const float* __restrict__ hfin, const float* __restrict__ Wd,
    const float* __restrict__ bd, float* __restrict__ out) {
  __shared__ float hrow[1024];
  __shared__ float red[256];
  int b = blockIdx.x, tid = threadIdx.x;
  float4 hv = *(const float4*)&hfin[(size_t)b * 1024 + tid * 4];
  hrow[tid * 4 + 0] = hv.x;
  hrow[tid * 4 + 1] = hv.y;
  hrow[tid * 4 + 2] = hv.z;
  hrow[tid * 4 + 3] = hv.w;
  __syncthreads();
  float vals[4];
#pragma unroll
  for (int chn = 0; chn < 4; ++chn) {
    int c = chn * 256 + tid;
    float a = -1e30f;
    if (c < C_) {
      a = bd[c];
#pragma unroll 4
      for (int k = 0; k < 1024; ++k) a += hrow[k] * Wd[k * 1000 + c];
    }
    vals[chn] = a;
  }
  float mx = fmaxf(fmaxf(vals[0], vals[1]), fmaxf(vals[2], vals[3]));
  red[tid] = mx;
  __syncthreads();
  for (int s = 128; s > 0; s >>= 1) {
    if (tid < s) red[tid] = fmaxf(red[tid], red[tid + s]);
    __syncthreads();
  }
  float M = red[0];
  __syncthreads();
  float ex[4];
  float sm = 0.f;
#pragma unroll
  for (int chn = 0; chn < 4; ++chn) {
    int c = chn * 256 + tid;
    ex[chn] = (c < C_) ? __expf(vals[chn] - M) : 0.f;
    sm += ex[chn];
  }
  red[tid] = sm;
  __syncthreads();
  for (int s = 128; s > 0; s >>= 1) {
    if (tid < s) red[tid] += red[tid + s];
    __syncthreads();
  }
  float inv = 1.f / red[0];
#pragma unroll
  for (int chn = 0; chn < 4; ++chn) {
    int c = chn * 256 + tid;
    if (c < C_) out[(size_t)b * C_ + c] = ex[chn] * inv;
  }
}

// ---------------- launch ----------------
extern "C" void kernel_launch(void* const* d_in, const int* in_sizes, int n_in,
                              void* d_out, int out_size, void* d_ws, size_t ws_size,
                              hipStream_t stream) {
  const float* x    = (const float*)d_in[0];
  const float* Wk   = (const float*)d_in[1];
  const float* Wr   = (const float*)d_in[2];
  const float* bias = (const float*)d_in[3];
  const float* Wd   = (const float*)d_in[4];
  const float* bd   = (const float*)d_in[5];
  float* out = (float*)d_out;

  // ws layout (bytes)
  const size_t OFF_WKT  = 0;          // 4,194,304
  const size_t OFF_WRT  = 4194304;    // 8,388,608
  const size_t OFF_XZG  = 12582912;   // 8,388,608
  const size_t OFF_HB   = 31457280;   // 262,144
  const size_t OFF_SY   = 31719424;   // 262,144 (sync counters)
  const size_t OFF_HF   = 31981568;   // 262,144
  const size_t NEED     = 32243712;

  if (ws_size < NEED) {
    hipMemsetAsync(d_out, 0x7F, (size_t)out_size * sizeof(float), stream);
    return;
  }

  char* ws = (char*)d_ws;
  unsigned short* WKT = (unsigned short*)(ws + OFF_WKT);
  unsigned short* WRT = (unsigned short*)(ws + OFF_WRT);
  unsigned short* XZG = (unsigned short*)(ws + OFF_XZG);
  unsigned short* HB  = (unsigned short*)(ws + OFF_HB);
  unsigned int* SYNC  = (unsigned int*)(ws + OFF_SY);
  float* HF = (float*)(ws + OFF_HF);

  hipMemsetAsync(HB, 0, 131072, stream);    // h0 = 0 (slot 0)
  hipMemsetAsync(SYNC, 0, 262144, stream);  // barrier counters

  k_transpose_bf16<<<dim3(G4_ / 64, F_ / 64), 256, 0, stream>>>(Wk, WKT, F_, G4_);
  k_transpose_bf16<<<dim3(G4_ / 64, U_ / 64), 256, 0, stream>>>(Wr, WRT, U_, G4_);

  // persistent fused recurrence: regular launch (graph-capturable), grid == #CUs
  k_persist<<<256, 256, 0, stream>>>(x, WKT, WRT, bias, XZG, HB, HF, SYNC);

  k_final<<<64, 256, 0, stream>>>(HF, Wd, bd, out);
}